// Round 2
// baseline (1497.589 us; speedup 1.0000x reference)
//
#include <hip/hip_runtime.h>
#include <hip/hip_bf16.h>
#include <stdint.h>

// ProjSolver: z_{t+1} = [u | relu(v)] (bias + z_t @ Wz^T), 16 iters,
// res = max|z_new @ A^T - b| with done-latch.
// Inputs f32: z 2048x2048, b 1024, A 1024x2048, Wz 2048x2048, Wb 2048x1024.
// Output f32: z_star (2048*2048) then curr_iter (=17.0f) at index 2048*2048.
// Compute path: cast to bf16 once, MFMA 16x16x32 bf16, f32 accumulate.
// d_out's bytes are used as scratch for the bf16 weights (Wz, A) during the
// iterations and only overwritten by the final output pass.

typedef __hip_bfloat16 bf16;
typedef __attribute__((ext_vector_type(8))) short short8;
typedef __attribute__((ext_vector_type(4))) float f32x4;

#define N_DIM 2048
#define K_DIM 2048
#define MRES  1024
#define FREE_NUM 1024
#define NTOT (2048*2048)
#define F_TOL 1e-6f
#define MAX_ITER 16

__device__ __forceinline__ void async_cp16(const void* g, void* l) {
  __builtin_amdgcn_global_load_lds(
      (const __attribute__((address_space(1))) unsigned int*)g,
      (__attribute__((address_space(3))) unsigned int*)l, 16, 0, 0);
}

// ---------------- f32 -> bf16 cast (4 elems/thread) ---------------------------
__global__ __launch_bounds__(256) void k_cast(
    const float* __restrict__ in, bf16* __restrict__ o, int n)
{
  int i = (blockIdx.x * 256 + threadIdx.x) * 4;
  if (i < n) {
    float4 v = *(const float4*)(in + i);
    o[i + 0] = __float2bfloat16(v.x);
    o[i + 1] = __float2bfloat16(v.y);
    o[i + 2] = __float2bfloat16(v.z);
    o[i + 3] = __float2bfloat16(v.w);
  }
}

// ---------------- bias_proj[j] = sum_m b[m] * Wb[j][m]  (f32) -----------------
__global__ __launch_bounds__(256) void k_bias(
    const float* __restrict__ b, const float* __restrict__ Wb,
    float* __restrict__ bias)
{
  const int j = blockIdx.x;
  const int tid = threadIdx.x;
  float s = 0.f;
  for (int m = tid; m < MRES; m += 256)
    s += b[m] * Wb[(size_t)j * MRES + m];
#pragma unroll
  for (int off = 32; off > 0; off >>= 1) s += __shfl_xor(s, off);
  __shared__ float red[4];
  const int w = tid >> 6, l = tid & 63;
  if (l == 0) red[w] = s;
  __syncthreads();
  if (tid == 0) bias[j] = red[0] + red[1] + red[2] + red[3];
}

// ---------------- GEMM1: Zout = gate(bias + Zin @ W^T) ------------------------
__global__ __launch_bounds__(256) void k_znew(
    const bf16* __restrict__ Zin, const bf16* __restrict__ W,
    const float* __restrict__ bias, bf16* __restrict__ Zout,
    const int* __restrict__ done_flag)
{
  __shared__ __align__(16) short sA[128*32];
  __shared__ __align__(16) short sB[128*32];
  const int tid = threadIdx.x;
  const int w = tid >> 6, l = tid & 63;
  const int q = l >> 4, lm = l & 15;
  const int wm = w >> 1, wn = w & 1;
  const int rowBase = blockIdx.y * 128;
  const int colBase = blockIdx.x * 128;

  f32x4 acc[4][4];
  f32x4 zero4 = {0.f, 0.f, 0.f, 0.f};
#pragma unroll
  for (int i = 0; i < 4; i++)
#pragma unroll
    for (int j = 0; j < 4; j++) acc[i][j] = zero4;

  for (int k0 = 0; k0 < K_DIM; k0 += 32) {
#pragma unroll
    for (int r = 0; r < 2; r++) {
      int c = tid + 256 * r;           // 16B chunk id, 512 chunks per tile
      int row = c >> 2, kc = c & 3;
      async_cp16(Zin + (size_t)(rowBase + row) * K_DIM + k0 + kc * 8, sA + c * 8);
      async_cp16(W   + (size_t)(colBase + row) * K_DIM + k0 + kc * 8, sB + c * 8);
    }
    __syncthreads();
    short8 af[4], bfr[4];
#pragma unroll
    for (int mr = 0; mr < 4; mr++)
      af[mr] = *(const short8*)(sA + (wm * 64 + mr * 16 + lm) * 32 + q * 8);
#pragma unroll
    for (int nc = 0; nc < 4; nc++)
      bfr[nc] = *(const short8*)(sB + (wn * 64 + nc * 16 + lm) * 32 + q * 8);
#pragma unroll
    for (int mr = 0; mr < 4; mr++)
#pragma unroll
      for (int nc = 0; nc < 4; nc++)
        acc[mr][nc] = __builtin_amdgcn_mfma_f32_16x16x32_bf16(
            af[mr], bfr[nc], acc[mr][nc], 0, 0, 0);
    __syncthreads();
  }

  const int dn = *done_flag;
#pragma unroll
  for (int mr = 0; mr < 4; mr++) {
#pragma unroll
    for (int nc = 0; nc < 4; nc++) {
      int gc = colBase + wn * 64 + nc * 16 + lm;
      int gr0 = rowBase + wm * 64 + mr * 16 + q * 4;
      float bv = bias[gc];
#pragma unroll
      for (int r = 0; r < 4; r++) {
        int gr = gr0 + r;
        float v = acc[mr][nc][r] + bv;
        if (gc >= FREE_NUM) v = fmaxf(v, 0.f);
        Zout[(size_t)gr * N_DIM + gc] =
            dn ? Zin[(size_t)gr * N_DIM + gc] : __float2bfloat16(v);
      }
    }
  }
}

// ---------------- GEMM2: res = max|Z @ A^T - b| -------------------------------
__global__ __launch_bounds__(256) void k_resid(
    const bf16* __restrict__ Z, const bf16* __restrict__ A,
    const float* __restrict__ bvec, unsigned* __restrict__ res_bits)
{
  __shared__ __align__(16) short sA[128*32];
  __shared__ __align__(16) short sB[128*32];
  __shared__ float wred[4];
  const int tid = threadIdx.x;
  const int w = tid >> 6, l = tid & 63;
  const int q = l >> 4, lm = l & 15;
  const int wm = w >> 1, wn = w & 1;
  const int rowBase = blockIdx.y * 128;
  const int colBase = blockIdx.x * 128;   // over MRES=1024

  f32x4 acc[4][4];
  f32x4 zero4 = {0.f, 0.f, 0.f, 0.f};
#pragma unroll
  for (int i = 0; i < 4; i++)
#pragma unroll
    for (int j = 0; j < 4; j++) acc[i][j] = zero4;

  for (int k0 = 0; k0 < K_DIM; k0 += 32) {
#pragma unroll
    for (int r = 0; r < 2; r++) {
      int c = tid + 256 * r;
      int row = c >> 2, kc = c & 3;
      async_cp16(Z + (size_t)(rowBase + row) * K_DIM + k0 + kc * 8, sA + c * 8);
      async_cp16(A + (size_t)(colBase + row) * K_DIM + k0 + kc * 8, sB + c * 8);
    }
    __syncthreads();
    short8 af[4], bfr[4];
#pragma unroll
    for (int mr = 0; mr < 4; mr++)
      af[mr] = *(const short8*)(sA + (wm * 64 + mr * 16 + lm) * 32 + q * 8);
#pragma unroll
    for (int nc = 0; nc < 4; nc++)
      bfr[nc] = *(const short8*)(sB + (wn * 64 + nc * 16 + lm) * 32 + q * 8);
#pragma unroll
    for (int mr = 0; mr < 4; mr++)
#pragma unroll
      for (int nc = 0; nc < 4; nc++)
        acc[mr][nc] = __builtin_amdgcn_mfma_f32_16x16x32_bf16(
            af[mr], bfr[nc], acc[mr][nc], 0, 0, 0);
    __syncthreads();
  }

  float mx = 0.f;
#pragma unroll
  for (int mr = 0; mr < 4; mr++) {
#pragma unroll
    for (int nc = 0; nc < 4; nc++) {
      int gc = colBase + wn * 64 + nc * 16 + lm;
      float bv = bvec[gc];
#pragma unroll
      for (int r = 0; r < 4; r++)
        mx = fmaxf(mx, fabsf(acc[mr][nc][r] - bv));
    }
  }
#pragma unroll
  for (int off = 32; off > 0; off >>= 1) mx = fmaxf(mx, __shfl_xor(mx, off));
  if (l == 0) wred[w] = mx;
  __syncthreads();
  if (tid == 0) {
    float m2 = fmaxf(fmaxf(wred[0], wred[1]), fmaxf(wred[2], wred[3]));
    atomicMax(res_bits, __float_as_uint(m2));  // ok: values non-negative
  }
}

// ---------------- small kernels ----------------------------------------------
__global__ void k_init(unsigned* f) { f[0] = 0u; f[1] = 0u; f[2] = 0u; }

__global__ void k_flags(unsigned* f) {
  float res = __uint_as_float(f[0]);
  unsigned d = f[1];
  if (!d) {
    f[2] = f[2] + 1u;             // iters += !done
    if (res <= F_TOL) f[1] = 1u;  // done |= (res <= tol)
  }
  f[0] = 0u;                      // reset res for next iteration
}

__global__ __launch_bounds__(256) void k_final(
    const bf16* __restrict__ z, const unsigned* __restrict__ iters,
    float* __restrict__ out)
{
  size_t i = (size_t)blockIdx.x * 256 + threadIdx.x;
  if (i < NTOT) out[i] = __bfloat162float(z[i]);
  else if (i == NTOT) out[i] = (float)(*iters + 1u);
}

// ---------------- launcher ----------------------------------------------------
extern "C" void kernel_launch(void* const* d_in, const int* in_sizes, int n_in,
                              void* d_out, int out_size, void* d_ws, size_t ws_size,
                              hipStream_t stream) {
  const float* z  = (const float*)d_in[0];
  const float* b  = (const float*)d_in[1];
  const float* A  = (const float*)d_in[2];
  const float* Wz = (const float*)d_in[3];
  const float* Wb = (const float*)d_in[4];
  float* out = (float*)d_out;

  // bf16 weight scratch lives in d_out's bytes (rewritten by k_final at end)
  bf16* Wzb = (bf16*)d_out;                    // 4M bf16 = 8 MB
  bf16* Ab  = Wzb + (size_t)NTOT;              // 2M bf16 = 4 MB  (total 12 MB <= 16 MB)

  char* ws = (char*)d_ws;
  unsigned* flags = (unsigned*)ws;             // [0]=res bits [1]=done [2]=iters
  float* bias = (float*)(ws + 256);            // 2048 f32
  bf16* buf0 = (bf16*)(ws + 256 + 2048 * sizeof(float));
  bf16* buf1 = buf0 + (size_t)NTOT;            // ws use ~16.01 MB

  k_init<<<1, 1, 0, stream>>>(flags);
  k_cast<<<NTOT / 1024, 256, 0, stream>>>(Wz, Wzb, NTOT);
  k_cast<<<(MRES * N_DIM) / 1024, 256, 0, stream>>>(A, Ab, MRES * N_DIM);
  k_cast<<<NTOT / 1024, 256, 0, stream>>>(z, buf1, NTOT);   // iter0 input in buf1
  k_bias<<<N_DIM, 256, 0, stream>>>(b, Wb, bias);

  for (int it = 0; it < MAX_ITER; it++) {
    const bf16* in = (it & 1) ? buf0 : buf1;   // it=0 reads buf1 (cast of z)
    bf16* o = (it & 1) ? buf1 : buf0;
    k_znew<<<dim3(16, 16), 256, 0, stream>>>(in, Wzb, bias, o,
                                             (const int*)(flags + 1));
    k_resid<<<dim3(8, 16), 256, 0, stream>>>(o, Ab, b, flags);
    k_flags<<<1, 1, 0, stream>>>(flags);
  }
  // it=15 (odd) writes buf1 -> final z lives in buf1
  k_final<<<(NTOT + 256) / 256 + 1, 256, 0, stream>>>(buf1, flags + 2, out);
}

// Round 3
// 1063.875 us; speedup vs baseline: 1.4077x; 1.4077x over previous
//
#include <hip/hip_runtime.h>
#include <hip/hip_bf16.h>
#include <stdint.h>

// ProjSolver: z_{t+1} = [u | relu(v)](bias + z_t @ Wz^T), 16 iters,
// res(t) = max|z_t @ A^T - b| with done-latch.
// R3 structure: one fused dispatch per iteration computes z(t-1) @ [Wz; A]^T
// (N = 2048 znew cols + 1024 resid cols = 3072) in 128x64 tiles -> 768 blocks
// = 3 blocks/CU (vs 1/CU in R2). Resid columns reduce to an atomic; the last
// resid block (ticket) updates done/iters in-kernel. The z-chain runs
// unconditionally; once done latches every subsequent dispatch early-exits,
// which preserves z(T*) in its ping-pong buffer (next overwrite of that
// buffer would be 2 dispatches later). k_final picks the right buffer.

typedef __hip_bfloat16 bf16;
typedef __attribute__((ext_vector_type(8))) short short8;
typedef __attribute__((ext_vector_type(4))) float f32x4;

#define N_DIM 2048
#define K_DIM 2048
#define MRES  1024
#define FREE_NUM 1024
#define NTOT (2048*2048)
#define F_TOL 1e-6f
#define MAX_ITER 16
#define NRB 256   // resid blocks: (1024/64) x-tiles * (2048/128) y-tiles

__device__ __forceinline__ void async_cp16(const void* g, void* l) {
  __builtin_amdgcn_global_load_lds(
      (const __attribute__((address_space(1))) unsigned int*)g,
      (__attribute__((address_space(3))) unsigned int*)l, 16, 0, 0);
}

// flags: [0]=res max bits, [1]=done, [2]=iters, [3]=ticket
__global__ void k_init(unsigned* f) { f[0]=0u; f[1]=0u; f[2]=0u; f[3]=0u; }

__global__ __launch_bounds__(256) void k_cast(
    const float* __restrict__ in, bf16* __restrict__ o, int n)
{
  int i = (blockIdx.x * 256 + threadIdx.x) * 4;
  if (i < n) {
    float4 v = *(const float4*)(in + i);
    o[i + 0] = __float2bfloat16(v.x);
    o[i + 1] = __float2bfloat16(v.y);
    o[i + 2] = __float2bfloat16(v.z);
    o[i + 3] = __float2bfloat16(v.w);
  }
}

__global__ __launch_bounds__(256) void k_bias(
    const float* __restrict__ b, const float* __restrict__ Wb,
    float* __restrict__ bias)
{
  const int j = blockIdx.x;
  const int tid = threadIdx.x;
  float s = 0.f;
  for (int m = tid; m < MRES; m += 256)
    s += b[m] * Wb[(size_t)j * MRES + m];
#pragma unroll
  for (int off = 32; off > 0; off >>= 1) s += __shfl_xor(s, off);
  __shared__ float red[4];
  const int w = tid >> 6, l = tid & 63;
  if (l == 0) red[w] = s;
  __syncthreads();
  if (tid == 0) bias[j] = red[0] + red[1] + red[2] + red[3];
}

// ---------------- fused step: C = Zin @ [Wz; A]^T, 128x64 tiles --------------
__global__ __launch_bounds__(256) void k_step(
    const bf16* __restrict__ Zin, const bf16* __restrict__ Wzb,
    const bf16* __restrict__ Ab, const float* __restrict__ bias,
    const float* __restrict__ bvec, bf16* __restrict__ Zout,
    unsigned* __restrict__ flags, int consume)
{
  __shared__ __align__(16) short sA[128 * 32];
  __shared__ __align__(16) short sB[64 * 32];
  __shared__ unsigned s_done;
  __shared__ float wred[4];
  __shared__ unsigned s_last;

  const int tid = threadIdx.x;
  if (tid == 0) s_done = flags[1];
  const int w = tid >> 6, l = tid & 63;
  const int q = l >> 4, lm = l & 15;
  const int wm = w >> 1, wn = w & 1;
  const int rowBase = blockIdx.y * 128;
  const int colBase = blockIdx.x * 64;
  const bool isZ = colBase < N_DIM;
  __syncthreads();
  const unsigned done0 = s_done;

  float mx = 0.f;
  if (!done0) {
    const bf16* Bp = isZ ? (Wzb + (size_t)colBase * K_DIM)
                         : (Ab + (size_t)(colBase - N_DIM) * K_DIM);
    f32x4 acc[4][2];
    f32x4 zero4 = {0.f, 0.f, 0.f, 0.f};
#pragma unroll
    for (int i = 0; i < 4; i++)
#pragma unroll
      for (int j = 0; j < 2; j++) acc[i][j] = zero4;

    for (int k0 = 0; k0 < K_DIM; k0 += 32) {
      // A tile: 128x32 bf16 = 512 16B-chunks (2/thread); B tile: 64x32 = 256
      {
        int c = tid, row = c >> 2, kc = c & 3;
        async_cp16(Zin + (size_t)(rowBase + row) * K_DIM + k0 + kc * 8, sA + c * 8);
        c = tid + 256; row = c >> 2; kc = c & 3;
        async_cp16(Zin + (size_t)(rowBase + row) * K_DIM + k0 + kc * 8, sA + c * 8);
        c = tid; row = c >> 2; kc = c & 3;
        async_cp16(Bp + (size_t)row * K_DIM + k0 + kc * 8, sB + c * 8);
      }
      __syncthreads();
      short8 af[4], bfr[2];
#pragma unroll
      for (int mr = 0; mr < 4; mr++)
        af[mr] = *(const short8*)(sA + (wm * 64 + mr * 16 + lm) * 32 + q * 8);
#pragma unroll
      for (int nc = 0; nc < 2; nc++)
        bfr[nc] = *(const short8*)(sB + (wn * 32 + nc * 16 + lm) * 32 + q * 8);
#pragma unroll
      for (int mr = 0; mr < 4; mr++)
#pragma unroll
        for (int nc = 0; nc < 2; nc++)
          acc[mr][nc] = __builtin_amdgcn_mfma_f32_16x16x32_bf16(
              af[mr], bfr[nc], acc[mr][nc], 0, 0, 0);
      __syncthreads();
    }

    if (isZ) {
#pragma unroll
      for (int mr = 0; mr < 4; mr++) {
#pragma unroll
        for (int nc = 0; nc < 2; nc++) {
          int gc = colBase + wn * 32 + nc * 16 + lm;
          int gr0 = rowBase + wm * 64 + mr * 16 + q * 4;
          float bv = bias[gc];
#pragma unroll
          for (int r = 0; r < 4; r++) {
            float v = acc[mr][nc][r] + bv;
            if (gc >= FREE_NUM) v = fmaxf(v, 0.f);
            Zout[(size_t)(gr0 + r) * N_DIM + gc] = __float2bfloat16(v);
          }
        }
      }
    } else {
#pragma unroll
      for (int mr = 0; mr < 4; mr++) {
#pragma unroll
        for (int nc = 0; nc < 2; nc++) {
          int rc = colBase - N_DIM + wn * 32 + nc * 16 + lm;
          float bv = bvec[rc];
#pragma unroll
          for (int r = 0; r < 4; r++)
            mx = fmaxf(mx, fabsf(acc[mr][nc][r] - bv));
        }
      }
    }
  }

  if (!isZ) {
    // block max -> device atomic; last resid block consumes + updates flags
#pragma unroll
    for (int off = 32; off > 0; off >>= 1) mx = fmaxf(mx, __shfl_xor(mx, off));
    if (l == 0) wred[w] = mx;
    __syncthreads();
    if (tid == 0) {
      if (!done0) {
        float m2 = fmaxf(fmaxf(wred[0], wred[1]), fmaxf(wred[2], wred[3]));
        atomicMax(flags, __float_as_uint(m2));  // values non-negative
      }
      __threadfence();
      unsigned tk = atomicAdd(flags + 3, 1u);
      s_last = (tk == NRB - 1) ? 1u : 0u;
    }
    __syncthreads();
    if (s_last && tid == 0) {
      unsigned rb = atomicMax(flags, 0u);       // coherent read of res max
      float res = __uint_as_float(rb);
      if (consume && flags[1] == 0u) {
        flags[2] += 1u;                          // iters++ for iteration t-1
        if (res <= F_TOL) flags[1] = 1u;         // done latch
      }
      flags[0] = 0u;                             // reset res slot
      flags[3] = 0u;                             // reset ticket
      __threadfence();
    }
  }
}

__global__ __launch_bounds__(256) void k_final(
    const bf16* __restrict__ z0, const bf16* __restrict__ z1,
    const unsigned* __restrict__ flags, float* __restrict__ out)
{
  size_t i = (size_t)blockIdx.x * 256 + threadIdx.x;
  unsigned done = flags[1], iters = flags[2];
  // never-done: z(16) lives in buf0; done at T*: z(T*) in buf[T* & 1]
  const bf16* src = done ? ((iters & 1u) ? z1 : z0) : z0;
  if (i < NTOT) out[i] = __bfloat162float(src[i]);
  else if (i == NTOT) out[i] = (float)(iters + (done ? 0u : 1u) + 1u);
}

// ---------------- launcher ----------------------------------------------------
extern "C" void kernel_launch(void* const* d_in, const int* in_sizes, int n_in,
                              void* d_out, int out_size, void* d_ws, size_t ws_size,
                              hipStream_t stream) {
  const float* z  = (const float*)d_in[0];
  const float* b  = (const float*)d_in[1];
  const float* A  = (const float*)d_in[2];
  const float* Wz = (const float*)d_in[3];
  const float* Wb = (const float*)d_in[4];
  float* out = (float*)d_out;

  // bf16 weights parked in d_out bytes (overwritten by k_final at the end)
  bf16* Wzb = (bf16*)d_out;                 // 8 MB
  bf16* Ab  = Wzb + (size_t)NTOT;           // 4 MB (12 MB <= 16 MB out buffer)

  char* ws = (char*)d_ws;                   // ~16.01 MB used (same as R2)
  unsigned* flags = (unsigned*)ws;
  float* bias = (float*)(ws + 256);
  bf16* buf0 = (bf16*)(ws + 256 + 2048 * sizeof(float));
  bf16* buf1 = buf0 + (size_t)NTOT;

  k_init<<<1, 1, 0, stream>>>(flags);
  k_cast<<<NTOT / 1024, 256, 0, stream>>>(Wz, Wzb, NTOT);
  k_cast<<<(MRES * N_DIM) / 1024, 256, 0, stream>>>(A, Ab, MRES * N_DIM);
  k_cast<<<NTOT / 1024, 256, 0, stream>>>(z, buf0, NTOT);   // z(0) -> buf0
  k_bias<<<N_DIM, 256, 0, stream>>>(b, Wb, bias);

  for (int t = 1; t <= MAX_ITER; t++) {
    const bf16* in = ((t - 1) & 1) ? buf1 : buf0;   // z(t-1)
    bf16* o = (t & 1) ? buf1 : buf0;                // z(t)
    // dispatch t: znew(t) on cols [0,2048) + resid(t-1) on cols [2048,3072)
    k_step<<<dim3(48, 16), 256, 0, stream>>>(in, Wzb, Ab, bias, b, o, flags,
                                             (t >= 2) ? 1 : 0);
  }
  k_final<<<(NTOT + 256) / 256 + 1, 256, 0, stream>>>(buf0, buf1, flags, out);
}